// Round 1
// baseline (100.567 us; speedup 1.0000x reference)
//
#include <hip/hip_runtime.h>

// Problem constants (from reference)
constexpr int L  = 250;   // layers
constexpr int T  = 600;   // traces
constexpr int A  = 30;    // angles
constexpr int AH = 15;    // angles per half-block (A/2)

typedef _Float16 h8  __attribute__((ext_vector_type(8)));   // MFMA A/B frag (4 VGPR)
typedef float    f4  __attribute__((ext_vector_type(4)));   // MFMA C/D frag

// refT LDS row stride (halfs): 264 = 256+8 -> 16-B aligned rows, 2-way-free banks
constexpr int RT_LD = 264;

// ---------------- Fused kernel: TWO blocks per trace (angle halves) ----------
// R15: attack the measured bottleneck — Occupancy 19.5% / VALUBusy 41% /
// MfmaUtil 2% / HBM 8% => latency-bound, too few waves (2400 on 256 CUs).
//   * Angle-split: block (t, half) computes 15 angles. Grid 1200 -> 4800
//     waves, ~4.7 blocks/CU, tail imbalance 1.28x -> 1.07x. Per-block
//     structure is byte-for-byte the proven R12 shape (4 waves, same phase-1
//     math, same verified MFMA layouts), just 1 n-tile instead of 2.
//     (R14's 512-thread variant was intermittently WRONG -> not retried.)
//   * R13's angle-split regressed with +40% WRITE_SIZE: sibling half-blocks
//     landed on different XCDs, so each 60-B half of an out[t][l][:] line was
//     written back from a different L2. Fix: halves are blockIdx b and b+600;
//     600 % 8 == 0 keeps both on the SAME XCD under round-robin dispatch, so
//     partial lines merge in L2. (Wrong mapping costs only WRITE_SIZE, not
//     correctness.)
//   * Phase-2 A-frag: clamp/zero-select logic is only needed at the K
//     boundary. ks=0..6 (cols <= 223 < 250) now use bare float2 loads + f16
//     casts; only ks=7 keeps the proven clamped-pair + zero-select path.
//     wrow pointers hoisted out of the ks loop. ~2x fewer phase-2 VALU ops.
//   * __launch_bounds__(256,5): cap VGPR <= ~102 so 5 blocks/CU residency
//     isn't register-capped; phase-1 unroll 2 -> 5 for ILP.
// NO workspace, NO producer kernel (R8-R11 non-deterministic handoff).
__global__ __launch_bounds__(256, 5)
void zoep_fused(const float* __restrict__ vp,
                const float* __restrict__ vs,
                const float* __restrict__ rho,
                const float* __restrict__ theta,
                const float* __restrict__ wm,
                float* __restrict__ out)
{
    __shared__ _Float16 refT[16 * RT_LD];   // 8.25 KB: refT[a_local][k], row 15 = zero pad
    __shared__ float sth_s[16];
    __shared__ float cth_s[16];

    const int tid   = threadIdx.x;
    const int bid   = blockIdx.x;
    const int half  = (bid >= T) ? 1 : 0;   // b and b+600 -> same trace, same XCD
    const int t     = bid - half * T;
    const int abase = half * AH;             // global angle offset of this block

    if (tid < 16) {
        const float th = (tid < AH) ? theta[abase + tid] : 0.0f;
        sth_s[tid] = sinf(th);
        cth_s[tid] = cosf(th);
    }
    __syncthreads();

    // ---- Phase 1: thread owns interface k = tid (0..255), 15 angles ----
    // Math body is verbatim R12 (proven: absmax 0.0039).
    const int  k     = tid;
    const bool valid = (k < L - 1);
    const int  kc    = valid ? k : (L - 2);   // clamped: loads always in-bounds

    const float a1 = vp[kc * T + t];          // lane-distinct lines, 1 instr/array
    const float a2 = vp[(kc + 1) * T + t];
    const float b1 = vs[kc * T + t];
    const float b2 = vs[(kc + 1) * T + t];
    const float r1 = rho[kc * T + t];
    const float r2 = rho[(kc + 1) * T + t];

    const float ra1  = __builtin_amdgcn_rcpf(a1);
    const float rb1  = r1 * b1, rb2 = r2 * b2;
    const float ra1r = r1 * a1, ra2r = r2 * a2;

#pragma unroll 5
    for (int a = 0; a < AH; ++a) {
        const float sth = sth_s[a];           // LDS broadcast (uniform a)
        const float cth = cth_s[a];

        const float p   = sth * ra1;
        const float s2  = p * a2;             // |.| <= 0.84 < 1 (input ranges)
        const float c2  = sqrtf(1.0f - s2 * s2);
        const float sp1 = p * b1;
        const float cp1 = sqrtf(1.0f - sp1 * sp1);
        const float sp2 = p * b2;
        const float cp2 = sqrtf(1.0f - sp2 * sp2);

        const float k1 = 1.0f - 2.0f * sp1 * sp1;
        const float k2 = 1.0f - 2.0f * sp2 * sp2;
        const float q1 = rb1 * k1;
        const float q2 = rb2 * k2;
        const float P1 = ra1r * k1;
        const float P2 = ra2r * k2;
        const float u1 = 2.0f * rb1 * sp1;
        const float u2 = 2.0f * rb2 * sp2;
        const float S1 = u1 * cp1;
        const float S2 = u2 * cp2;
        const float g1 = u1 * cth;
        const float g2 = u2 * c2;

        // M (row-major)
        const float m00 = -sth, m01 = -cp1, m02 = s2,  m03 = cp2;
        const float m10 =  cth, m11 = -sp1, m12 = c2,  m13 = -sp2;
        const float m20 =  g1,  m21 =  q1,  m22 = g2,  m23 = q2;
        const float m30 = -P1,  m31 =  S1,  m32 = P2,  m33 = -S2;

        // 2x2 minors: s* rows{0,1}, c* rows{2,3}
        const float s3v = m01 * m12 - m11 * m02;
        const float s4v = m01 * m13 - m11 * m03;
        const float s5v = m02 * m13 - m12 * m03;
        const float c3v = m21 * m32 - m31 * m22;
        const float c4v = m21 * m33 - m31 * m23;
        const float c5v = m22 * m33 - m32 * m23;
        const float s0v = m00 * m11 - m10 * m01;
        const float s1v = m00 * m12 - m10 * m02;
        const float s2v = m00 * m13 - m10 * m03;
        const float c0v = m20 * m31 - m30 * m21;
        const float c1v = m20 * m32 - m30 * m22;
        const float c2v = m20 * m33 - m30 * m23;

        const float detM = s0v*c5v - s1v*c4v + s2v*c3v
                         + s3v*c2v - s4v*c1v + s5v*c0v;
        const float A0 = m11*c5v - m12*c4v + m13*c3v;   // minor(0,0)
        const float A3 = m21*s5v - m22*s4v + m23*s3v;   // minor(3,0)

        const float num = m00 * A0 - m30 * A3;
        const float res = 1.0f - 2.0f * num * __builtin_amdgcn_rcpf(detM);

        refT[a * RT_LD + k] = (_Float16)(valid ? res : 0.0f);
    }
    // zero pad row a_local = 15 (read by B-frag lane n16==15)
    refT[AH * RT_LD + k] = (_Float16)0.0f;
    __syncthreads();

    // ---- Phase 2: MFMA GEMM. wave w owns m-tiles w*4..w*4+3, ONE n-tile.
    // Verified layouts (R12): A[m=lane&15][k=quad*8+j], B[k=quad*8+j][n=lane&15],
    // C/D[row=quad*4+reg][col=lane&15].
    const int w    = tid >> 6;       // wave 0..3
    const int lane = tid & 63;
    const int quad = lane >> 4;      // 0..3
    const int n16  = lane & 15;

    f4 acc[4];
#pragma unroll
    for (int mi = 0; mi < 4; ++mi) acc[mi] = (f4){0.f, 0.f, 0.f, 0.f};

    // Hoisted, clamped wm row pointers (store-masked at epilogue for m >= L)
    const float* wrow[4];
#pragma unroll
    for (int mi = 0; mi < 4; ++mi) {
        const int m = (w * 4 + mi) * 16 + n16;        // logical wm row 0..255
        wrow[mi] = wm + ((m < L) ? m : (L - 1)) * L;
    }

    // ks = 0..6: every col = kofs..kofs+7 <= 223 < 250 -> no clamps, no selects.
    // wm rows are 1000 B (8B-aligned only for odd rows) -> float2 loads.
#pragma unroll
    for (int ks = 0; ks < 7; ++ks) {
        const int kofs = ks * 32 + quad * 8;
        const h8 b0 = *(const h8*)&refT[n16 * RT_LD + kofs];
#pragma unroll
        for (int mi = 0; mi < 4; ++mi) {
            const float2 f0 = *(const float2*)(wrow[mi] + kofs);
            const float2 f1 = *(const float2*)(wrow[mi] + kofs + 2);
            const float2 f2 = *(const float2*)(wrow[mi] + kofs + 4);
            const float2 f3 = *(const float2*)(wrow[mi] + kofs + 6);
            const h8 af = { (_Float16)f0.x, (_Float16)f0.y,
                            (_Float16)f1.x, (_Float16)f1.y,
                            (_Float16)f2.x, (_Float16)f2.y,
                            (_Float16)f3.x, (_Float16)f3.y };
            acc[mi] = __builtin_amdgcn_mfma_f32_16x16x32_f16(af, b0, acc[mi], 0, 0, 0);
        }
    }
    { // ks = 7: cols 224..255 — only quad==3 (cols 248..255) is partial.
      // Proven R12 boundary path: pair-clamp keeps loads in wm[0..62499],
      // zero-select keeps cols >= 250 finite (they hit zero refT columns).
        const int kofs = 224 + quad * 8;
        const h8 b0 = *(const h8*)&refT[n16 * RT_LD + kofs];
#pragma unroll
        for (int mi = 0; mi < 4; ++mi) {
            h8 af;
#pragma unroll
            for (int c = 0; c < 4; ++c) {
                const int col  = kofs + 2 * c;                    // even
                const int colc = (col <= L - 2) ? col : (L - 2);  // pair start <= 248
                const float2 f = *(const float2*)(wrow[mi] + colc); // 8B-aligned
                af[2 * c]     = (_Float16)((col     < L) ? f.x : 0.0f);
                af[2 * c + 1] = (_Float16)((col + 1 < L) ? f.y : 0.0f);
            }
            acc[mi] = __builtin_amdgcn_mfma_f32_16x16x32_f16(af, b0, acc[mi], 0, 0, 0);
        }
    }

    // ---- Epilogue: D[row=quad*4+r][col=n16] -> out[t][l][abase + n16] ----
    // n16 == 15 maps to the zero-pad refT row -> never stored.
    float* outt = out + (size_t)t * (L * A) + abase;
    if (n16 < AH) {
#pragma unroll
        for (int mi = 0; mi < 4; ++mi) {
            const int mbase = (w * 4 + mi) * 16 + quad * 4;
#pragma unroll
            for (int r = 0; r < 4; ++r) {
                const int l = mbase + r;
                if (l < L) outt[l * A + n16] = acc[mi][r];
            }
        }
    }
}

extern "C" void kernel_launch(void* const* d_in, const int* in_sizes, int n_in,
                              void* d_out, int out_size, void* d_ws, size_t ws_size,
                              hipStream_t stream) {
    (void)in_sizes; (void)n_in; (void)out_size; (void)d_ws; (void)ws_size;
    const float* vp    = (const float*)d_in[0];
    const float* vs    = (const float*)d_in[1];
    const float* rho   = (const float*)d_in[2];
    const float* theta = (const float*)d_in[3];
    const float* wm    = (const float*)d_in[4];
    float* out = (float*)d_out;

    // Grid 2*T: block b and b+T are the two angle-halves of trace b.
    // 600 % 8 == 0 -> both land on the same XCD (round-robin), merging the
    // two 60-B halves of each out[t][l][:] cache line in one L2.
    zoep_fused<<<dim3(2 * T), dim3(256), 0, stream>>>(vp, vs, rho, theta, wm, out);
}